// Round 7
// baseline (682.069 us; speedup 1.0000x reference)
//
#include <hip/hip_runtime.h>

// VectorQuantizer on MI355X — round 7: pipelined MFMA screen (dbuf B, 1 barrier/phase,
// barrier-free superset epilogue) + exact fp32 rescore.
// z: (64,256,32,32) f32; emb: (1024,256) f32.
// out (f32): [0,16777216) z_q_out | [16777216] loss | [16777217,+65536) indices
//
// ws layout (bytes):
//   0        double   loss_acc                 (memset 0)
//   64       int      widx[65536]
//   262208   float    e2[1024]                 (numpy-pairwise fp32)
//   266304   float    z2[65536]                (numpy-pairwise fp32)
//   528448   int      gcnt[65536]
//   790592   ushort   gcand[65536*16]
//   2887744  _Float16 Ef[1024*256]             (f16 RNE copy of emb)

typedef _Float16 f16x8 __attribute__((ext_vector_type(8)));
typedef float f32x4 __attribute__((ext_vector_type(4)));

#define VQ_W 1.5e-3f
#define SCR_LDS_BYTES 68096
#define RES_LDS_BYTES (65792 + 512)
#define OUT_LDS_BYTES 66560

// fl32(v*v) with a barrier so the product cannot be contracted into a later add.
__device__ __forceinline__ float sq_rnd(float v) {
  float y = v * v;
  asm volatile("" : "+v"(y));
  return y;
}

// numpy pairwise_sum over 256 fp32 squared terms (8-accumulator blocks of 128).
__device__ float np_pw256_sq(const float* base, int stride) {
  float tot0, tot1;
  {
    const float* a = base;
    float r[8];
    #pragma unroll
    for (int j = 0; j < 8; ++j) r[j] = sq_rnd(a[j * stride]);
    #pragma unroll 1
    for (int i = 8; i < 128; i += 8) {
      #pragma unroll
      for (int j = 0; j < 8; ++j) r[j] += sq_rnd(a[(i + j) * stride]);
    }
    tot0 = ((r[0] + r[1]) + (r[2] + r[3])) + ((r[4] + r[5]) + (r[6] + r[7]));
  }
  {
    const float* a = base + 128 * stride;
    float r[8];
    #pragma unroll
    for (int j = 0; j < 8; ++j) r[j] = sq_rnd(a[j * stride]);
    #pragma unroll 1
    for (int i = 8; i < 128; i += 8) {
      #pragma unroll
      for (int j = 0; j < 8; ++j) r[j] += sq_rnd(a[(i + j) * stride]);
    }
    tot1 = ((r[0] + r[1]) + (r[2] + r[3])) + ((r[4] + r[5]) + (r[6] + r[7]));
  }
  return tot0 + tot1;
}

__global__ __launch_bounds__(256) void vq_prep(const float* __restrict__ emb,
                                               _Float16* __restrict__ Ef,
                                               float* __restrict__ e2) {
  const int g = blockIdx.x * 256 + threadIdx.x;  // 0..262143
  Ef[g] = (_Float16)emb[g];                      // RNE v_cvt_f16_f32
  if (g < 1024) e2[g] = np_pw256_sq(emb + g * 256, 1);
}

// |z|^2 per point, numpy-pairwise. 4 points/thread via float4 along hw. (r3-verified)
__global__ __launch_bounds__(256) void vq_z2(const float* __restrict__ z,
                                             float* __restrict__ z2) {
  const int t4 = blockIdx.x * 256 + threadIdx.x;  // 0..16383
  const int n0 = t4 * 4;
  const int bb = n0 >> 10, hw = n0 & 1023;
  const float* zp = z + bb * 262144 + hw;
  float r0[4][8], r1[4][8];
  #pragma unroll
  for (int p = 0; p < 4; ++p)
    #pragma unroll
    for (int j = 0; j < 8; ++j) { r0[p][j] = 0.f; r1[p][j] = 0.f; }
  #pragma unroll 1
  for (int d8 = 0; d8 < 128; d8 += 8) {
    #pragma unroll
    for (int j = 0; j < 8; ++j) {
      const float4 v = *(const float4*)&zp[(d8 + j) * 1024];
      r0[0][j] += sq_rnd(v.x); r0[1][j] += sq_rnd(v.y);
      r0[2][j] += sq_rnd(v.z); r0[3][j] += sq_rnd(v.w);
    }
  }
  #pragma unroll 1
  for (int d8 = 128; d8 < 256; d8 += 8) {
    #pragma unroll
    for (int j = 0; j < 8; ++j) {
      const float4 v = *(const float4*)&zp[(d8 + j) * 1024];
      r1[0][j] += sq_rnd(v.x); r1[1][j] += sq_rnd(v.y);
      r1[2][j] += sq_rnd(v.z); r1[3][j] += sq_rnd(v.w);
    }
  }
  #pragma unroll
  for (int p = 0; p < 4; ++p) {
    const float t0 = ((r0[p][0] + r0[p][1]) + (r0[p][2] + r0[p][3])) +
                     ((r0[p][4] + r0[p][5]) + (r0[p][6] + r0[p][7]));
    const float t1 = ((r1[p][0] + r1[p][1]) + (r1[p][2] + r1[p][3])) +
                     ((r1[p][4] + r1[p][5]) + (r1[p][6] + r1[p][7]));
    z2[n0 + p] = t0 + t1;
  }
}

// Screening v2: f16 MFMA, block = 64 points x 1024 codes.
// A (z) resident in LDS [64][256] f16, rows XOR-swizzled by (row&7) on 16B slots.
// B (codes) double-buffered 16KB tiles: 256 codes x 32 k per phase, rows 64B with
// slot swizzle: LDS slot s of row r holds k-octet s^(r&3); read slot q^(r&3).
// 32 phases (4 chunks x 8), 2-deep reg staging, ONE barrier per phase.
// Epilogue per chunk, barrier-free: thr = min(wave_min, stale_global_min) + W
// (stale reads only loosen -> candidate superset preserved).
__global__ __launch_bounds__(256, 2) void vq_screen(
    const float* __restrict__ z, const _Float16* __restrict__ Ef,
    const float* __restrict__ e2, const float* __restrict__ z2,
    int* __restrict__ gcnt, unsigned short* __restrict__ gcand) {
  extern __shared__ __align__(16) char smem[];
  // [0,32768) A; [32768,65536) B dbuf; 65536 runminU[64]; 65792 cnt[64]; 66048 cand[64][16]
  unsigned* runminU = (unsigned*)(smem + 65536);
  int* cnt = (int*)(smem + 65792);
  unsigned short* cand = (unsigned short*)(smem + 66048);

  const int tid = threadIdx.x;
  const int blk = blockIdx.x;
  const int n0 = blk * 64;
  const int bb = blk >> 4;
  const int hw0 = (blk & 15) * 64;
  const float* zb = z + bb * 262144 + hw0;

  if (tid < 64) { runminU[tid] = 0x7F800000u; cnt[tid] = 0; }

  {  // A stage: convert z tile to f16, swizzled rows
    const int p = tid & 63, dh = tid >> 6;
    #pragma unroll
    for (int dq = 0; dq < 8; ++dq) {
      const int d0 = dh * 64 + dq * 8;
      f16x8 hv;
      #pragma unroll
      for (int j = 0; j < 8; ++j) hv[j] = (_Float16)zb[(d0 + j) * 1024 + p];
      *(f16x8*)&smem[p * 512 + ((d0 * 2) ^ ((p & 7) * 16))] = hv;
    }
  }

  const int l = tid & 63;
  const int ln = l & 15;
  const int q = l >> 4;
  const int wc = tid >> 6;        // wave: codes wc*64 .. +63 per chunk
  const int xr = (l & 7) * 16;
  const int bswz = (l & 3) * 16;

  float z2r[4][4];
  #pragma unroll
  for (int fi = 0; fi < 4; ++fi)
    #pragma unroll
    for (int rg = 0; rg < 4; ++rg)
      z2r[fi][rg] = z2[n0 + fi * 16 + q * 4 + rg];

  f32x4 acc[4][4];
  #pragma unroll
  for (int fi = 0; fi < 4; ++fi)
    #pragma unroll
    for (int fj = 0; fj < 4; ++fj) acc[fi][fj] = (f32x4){0.f, 0.f, 0.f, 0.f};

  f16x8 stg[4];
  // prologue: tile 0 -> B0 ; tile 1 -> regs
  #pragma unroll
  for (int it = 0; it < 4; ++it) {
    const int c2 = it * 256 + tid;
    const int r = c2 >> 2, s = c2 & 3;
    stg[it] = *(const f16x8*)&Ef[r * 256 + (s ^ (r & 3)) * 8];  // t=0: cc=0,ph=0
  }
  #pragma unroll
  for (int it = 0; it < 4; ++it)
    *(f16x8*)&smem[32768 + it * 4096 + tid * 16] = stg[it];
  #pragma unroll
  for (int it = 0; it < 4; ++it) {
    const int c2 = it * 256 + tid;
    const int r = c2 >> 2, s = c2 & 3;
    stg[it] = *(const f16x8*)&Ef[r * 256 + 32 + (s ^ (r & 3)) * 8];  // t=1: ph=1
  }
  __syncthreads();

  for (int p = 0; p < 32; ++p) {
    char* Bw = smem + 32768 + (((p & 1) ^ 1) << 14);
    const char* Br = smem + 32768 + ((p & 1) << 14);
    if (p < 31) {  // ds_write tile p+1 (buffer read last in phase p-1; barrier passed)
      #pragma unroll
      for (int it = 0; it < 4; ++it)
        *(f16x8*)&Bw[it * 4096 + tid * 16] = stg[it];
    }
    if (p < 30) {  // issue global loads for tile p+2 (lands during next phase)
      const int t = p + 2;
      const int cct = t >> 3, pht = t & 7;
      #pragma unroll
      for (int it = 0; it < 4; ++it) {
        const int c2 = it * 256 + tid;
        const int r = c2 >> 2, s = c2 & 3;
        stg[it] = *(const f16x8*)&Ef[(cct * 256 + r) * 256 + pht * 32 +
                                     (s ^ (r & 3)) * 8];
      }
    }
    {  // compute phase p from Br
      const int ph = p & 7;
      f16x8 aF[4], bF[4];
      const int ab = (ph * 64 + q * 16) ^ xr;
      #pragma unroll
      for (int fi = 0; fi < 4; ++fi)
        aF[fi] = *(const f16x8*)&smem[(fi * 16 + ln) * 512 + ab];
      const int qb = (q * 16) ^ bswz;
      #pragma unroll
      for (int fj = 0; fj < 4; ++fj)
        bF[fj] = *(const f16x8*)&Br[(wc * 64 + fj * 16 + ln) * 64 + qb];
      #pragma unroll
      for (int fi = 0; fi < 4; ++fi)
        #pragma unroll
        for (int fj = 0; fj < 4; ++fj)
          acc[fi][fj] = __builtin_amdgcn_mfma_f32_16x16x32_f16(
              aF[fi], bF[fj], acc[fi][fj], 0, 0, 0);
    }
    if ((p & 7) == 7) {  // chunk epilogue (no barriers)
      const int cc = p >> 3;
      const int cbase = cc * 256 + wc * 64 + ln;
      float e2v[4];
      #pragma unroll
      for (int fj = 0; fj < 4; ++fj) e2v[fj] = e2[cbase + fj * 16];
      #pragma unroll
      for (int fi = 0; fi < 4; ++fi) {
        float sv[4][4];
        #pragma unroll
        for (int fj = 0; fj < 4; ++fj)
          #pragma unroll
          for (int rg = 0; rg < 4; ++rg)
            sv[fj][rg] = fmaf(-2.f, acc[fi][fj][rg], z2r[fi][rg] + e2v[fj]);
        #pragma unroll
        for (int rg = 0; rg < 4; ++rg) {
          float rm = fminf(fminf(sv[0][rg], sv[1][rg]), fminf(sv[2][rg], sv[3][rg]));
          rm = fminf(rm, __shfl_xor(rm, 1));
          rm = fminf(rm, __shfl_xor(rm, 2));
          rm = fminf(rm, __shfl_xor(rm, 4));
          rm = fminf(rm, __shfl_xor(rm, 8));
          const int row = fi * 16 + q * 4 + rg;
          if (ln == 0) atomicMin(&runminU[row], __float_as_uint(rm));
          const float g = __uint_as_float(runminU[row]);  // stale-ok (superset)
          const float thr = fminf(rm, g) + VQ_W;
          #pragma unroll
          for (int fj = 0; fj < 4; ++fj)
            if (sv[fj][rg] <= thr) {
              const int slot = atomicAdd(&cnt[row], 1);
              if (slot < 16)
                cand[row * 16 + slot] = (unsigned short)(cbase + fj * 16);
            }
        }
        #pragma unroll
        for (int fj = 0; fj < 4; ++fj) acc[fi][fj] = (f32x4){0.f, 0.f, 0.f, 0.f};
      }
    }
    __syncthreads();
  }

  if (tid < 64) gcnt[n0 + tid] = cnt[tid];
  {
    const int rr = tid >> 2, si = (tid & 3) * 4;
    *(uint2*)&gcand[(n0 + rr) * 16 + si] = *(const uint2*)&cand[rr * 16 + si];
  }
}

// Rescore (r6-verified): block = 64 points, z-tile in LDS, 4 threads/point split
// candidates; merge via LDS u64 atomicMin on (score_bits<<10)|k. Also writes the
// indices output directly.
__global__ __launch_bounds__(256) void vq_rescore(
    const float* __restrict__ z, const float* __restrict__ emb,
    const float* __restrict__ e2, const float* __restrict__ z2,
    const int* __restrict__ gcnt, const unsigned short* __restrict__ gcand,
    int* __restrict__ widx, float* __restrict__ out) {
  extern __shared__ __align__(16) char rsmem[];
  float* zt = (float*)rsmem;                                        // [64][257]
  unsigned long long* best = (unsigned long long*)(rsmem + 65792);  // [64]

  const int tid = threadIdx.x;
  const int w = tid >> 6;
  const int l = tid & 63;
  const int n0 = blockIdx.x << 6;
  const int bb = n0 >> 10, hw0 = n0 & 1023;
  const int n = n0 + l;

  const int c = gcnt[n];
  if (!__any(c >= 2)) {  // block-uniform: all waves see identical l-range
    if (w == 0) {
      const int v = gcand[n * 16];
      widx[n] = v;
      out[16777217 + n] = (float)v;
    }
    return;
  }

  {  // stage z tile
    const float* zb = z + bb * 262144 + hw0;
    #pragma unroll 8
    for (int it = 0; it < 64; ++it) {
      const int d = it * 4 + w;
      zt[l * 257 + d] = zb[d * 1024 + l];
    }
  }
  if (tid < 64) best[tid] = ~0ULL;
  __syncthreads();

  if (c >= 2) {
    const float z2n = z2[n];
    const float* zrow = &zt[l * 257];
    if (c <= 16) {
      for (int s = w; s < c; s += 4) {
        const int k = gcand[n * 16 + s];
        const float* ep = emb + k * 256;
        float a = 0.f;
        #pragma unroll 4
        for (int d = 0; d < 256; ++d) a = fmaf(zrow[d], ep[d], a);
        const float sv = fmaf(-2.f, a, z2n + e2[k]);
        const unsigned long long key =
            ((unsigned long long)__float_as_uint(sv) << 10) | (unsigned)k;
        atomicMin(&best[l], key);
      }
    } else {  // overflow fallback: exact full scan
      for (int k = w; k < 1024; k += 4) {
        const float* ep = emb + k * 256;
        float a = 0.f;
        #pragma unroll 4
        for (int d = 0; d < 256; ++d) a = fmaf(zrow[d], ep[d], a);
        const float sv = fmaf(-2.f, a, z2n + e2[k]);
        const unsigned long long key =
            ((unsigned long long)__float_as_uint(sv) << 10) | (unsigned)k;
        atomicMin(&best[l], key);
      }
    }
  }
  __syncthreads();
  if (tid < 64) {
    const int cc = gcnt[n0 + tid];
    const int v = (cc == 1) ? (int)gcand[(n0 + tid) * 16]
                            : (int)(best[tid] & 1023ULL);
    widx[n0 + tid] = v;
    out[16777217 + n0 + tid] = (float)v;
  }
}

// Output + loss (r3-verified). Gather 64 emb rows into LDS row-coalesced, then
// transpose-read (stride 260) + coalesced global write.
__global__ __launch_bounds__(256) void vq_out(const float* __restrict__ z,
                                              const float* __restrict__ emb,
                                              const int* __restrict__ widx,
                                              float* __restrict__ out,
                                              double* __restrict__ acc) {
  extern __shared__ float rows[];  // [64][260]
  const int tid = threadIdx.x;
  const int w = tid >> 6, l = tid & 63;
  const int n0 = blockIdx.x << 6;
  const int bb = n0 >> 10, hw0 = n0 & 1023;

  #pragma unroll 4
  for (int rr = 0; rr < 16; ++rr) {
    const int r = rr * 4 + w;
    const int idx = widx[n0 + r];
    const float4 ev = *(const float4*)&emb[idx * 256 + l * 4];
    *(float4*)&rows[r * 260 + l * 4] = ev;
  }
  __syncthreads();

  const int zofs = bb * 262144 + hw0 + l;
  const float* zp = z + zofs;
  float* op = out + zofs;
  double ls = 0.0;
  #pragma unroll 2
  for (int i16 = 0; i16 < 16; ++i16) {
    const int d4 = w * 64 + i16 * 4;
    const float4 q4 = *(const float4*)&rows[l * 260 + d4];
    #pragma unroll
    for (int e = 0; e < 4; ++e) {
      const int d = d4 + e;
      const float zv = zp[d * 1024];
      const float qv = ((const float*)&q4)[e];
      float df = qv - zv;
      asm volatile("" : "+v"(df));
      op[d * 1024] = zv + df;  // fl(z + fl(z_q - z))
      ls += (double)df * df;
    }
  }
  #pragma unroll
  for (int off = 32; off > 0; off >>= 1) ls += __shfl_down(ls, off);
  if (l == 0) atomicAdd(acc, ls);
}

__global__ void vq_fin(const double* __restrict__ acc, float* __restrict__ out) {
  if (threadIdx.x == 0)
    out[16777216] = (float)(1.25 * (*acc) * (1.0 / 16777216.0));
}

extern "C" void kernel_launch(void* const* d_in, const int* in_sizes, int n_in,
                              void* d_out, int out_size, void* d_ws, size_t ws_size,
                              hipStream_t stream) {
  const float* z = (const float*)d_in[0];
  const float* emb = (const float*)d_in[1];
  float* out = (float*)d_out;
  char* ws = (char*)d_ws;
  double* acc = (double*)(ws);
  int* widx = (int*)(ws + 64);
  float* e2 = (float*)(ws + 262208);
  float* z2 = (float*)(ws + 266304);
  int* gcnt = (int*)(ws + 528448);
  unsigned short* gcand = (unsigned short*)(ws + 790592);
  _Float16* Ef = (_Float16*)(ws + 2887744);

  hipFuncSetAttribute(reinterpret_cast<const void*>(vq_screen),
                      hipFuncAttributeMaxDynamicSharedMemorySize, SCR_LDS_BYTES);
  hipFuncSetAttribute(reinterpret_cast<const void*>(vq_rescore),
                      hipFuncAttributeMaxDynamicSharedMemorySize, RES_LDS_BYTES);
  hipFuncSetAttribute(reinterpret_cast<const void*>(vq_out),
                      hipFuncAttributeMaxDynamicSharedMemorySize, OUT_LDS_BYTES);

  hipMemsetAsync(ws, 0, 64, stream);
  vq_prep<<<1024, 256, 0, stream>>>(emb, Ef, e2);
  vq_z2<<<64, 256, 0, stream>>>(z, z2);
  vq_screen<<<1024, 256, SCR_LDS_BYTES, stream>>>(z, Ef, e2, z2, gcnt, gcand);
  vq_rescore<<<1024, 256, RES_LDS_BYTES, stream>>>(z, emb, e2, z2, gcnt, gcand,
                                                   widx, out);
  vq_out<<<1024, 256, OUT_LDS_BYTES, stream>>>(z, emb, widx, out, acc);
  vq_fin<<<1, 64, 0, stream>>>(acc, out);
}

// Round 8
// 626.330 us; speedup vs baseline: 1.0890x; 1.0890x over previous
//
#include <hip/hip_runtime.h>

// VectorQuantizer on MI355X — round 8: pipelined MFMA screen with FIXED epilogue
// (wave-local running min across chunks -> candidate superset w/o barriers).
// z: (64,256,32,32) f32; emb: (1024,256) f32.
// out (f32): [0,16777216) z_q_out | [16777216] loss | [16777217,+65536) indices
//
// ws layout (bytes):
//   0        double   loss_acc                 (memset 0)
//   64       int      widx[65536]
//   262208   float    e2[1024]                 (numpy-pairwise fp32)
//   266304   float    z2[65536]                (numpy-pairwise fp32)
//   528448   int      gcnt[65536]
//   790592   ushort   gcand[65536*16]
//   2887744  _Float16 Ef[1024*256]             (f16 RNE copy of emb)

typedef _Float16 f16x8 __attribute__((ext_vector_type(8)));
typedef float f32x4 __attribute__((ext_vector_type(4)));

#define VQ_W 1.5e-3f
#define SCR_LDS_BYTES 68096
#define RES_LDS_BYTES (65792 + 512)
#define OUT_LDS_BYTES 66560

// fl32(v*v) with a barrier so the product cannot be contracted into a later add.
__device__ __forceinline__ float sq_rnd(float v) {
  float y = v * v;
  asm volatile("" : "+v"(y));
  return y;
}

// numpy pairwise_sum over 256 fp32 squared terms (8-accumulator blocks of 128).
__device__ float np_pw256_sq(const float* base, int stride) {
  float tot0, tot1;
  {
    const float* a = base;
    float r[8];
    #pragma unroll
    for (int j = 0; j < 8; ++j) r[j] = sq_rnd(a[j * stride]);
    #pragma unroll 1
    for (int i = 8; i < 128; i += 8) {
      #pragma unroll
      for (int j = 0; j < 8; ++j) r[j] += sq_rnd(a[(i + j) * stride]);
    }
    tot0 = ((r[0] + r[1]) + (r[2] + r[3])) + ((r[4] + r[5]) + (r[6] + r[7]));
  }
  {
    const float* a = base + 128 * stride;
    float r[8];
    #pragma unroll
    for (int j = 0; j < 8; ++j) r[j] = sq_rnd(a[j * stride]);
    #pragma unroll 1
    for (int i = 8; i < 128; i += 8) {
      #pragma unroll
      for (int j = 0; j < 8; ++j) r[j] += sq_rnd(a[(i + j) * stride]);
    }
    tot1 = ((r[0] + r[1]) + (r[2] + r[3])) + ((r[4] + r[5]) + (r[6] + r[7]));
  }
  return tot0 + tot1;
}

__global__ __launch_bounds__(256) void vq_prep(const float* __restrict__ emb,
                                               _Float16* __restrict__ Ef,
                                               float* __restrict__ e2) {
  const int g = blockIdx.x * 256 + threadIdx.x;  // 0..262143
  Ef[g] = (_Float16)emb[g];                      // RNE v_cvt_f16_f32
  if (g < 1024) e2[g] = np_pw256_sq(emb + g * 256, 1);
}

// |z|^2 per point, numpy-pairwise. 4 points/thread via float4 along hw. (r3-verified)
__global__ __launch_bounds__(256) void vq_z2(const float* __restrict__ z,
                                             float* __restrict__ z2) {
  const int t4 = blockIdx.x * 256 + threadIdx.x;  // 0..16383
  const int n0 = t4 * 4;
  const int bb = n0 >> 10, hw = n0 & 1023;
  const float* zp = z + bb * 262144 + hw;
  float r0[4][8], r1[4][8];
  #pragma unroll
  for (int p = 0; p < 4; ++p)
    #pragma unroll
    for (int j = 0; j < 8; ++j) { r0[p][j] = 0.f; r1[p][j] = 0.f; }
  #pragma unroll 1
  for (int d8 = 0; d8 < 128; d8 += 8) {
    #pragma unroll
    for (int j = 0; j < 8; ++j) {
      const float4 v = *(const float4*)&zp[(d8 + j) * 1024];
      r0[0][j] += sq_rnd(v.x); r0[1][j] += sq_rnd(v.y);
      r0[2][j] += sq_rnd(v.z); r0[3][j] += sq_rnd(v.w);
    }
  }
  #pragma unroll 1
  for (int d8 = 128; d8 < 256; d8 += 8) {
    #pragma unroll
    for (int j = 0; j < 8; ++j) {
      const float4 v = *(const float4*)&zp[(d8 + j) * 1024];
      r1[0][j] += sq_rnd(v.x); r1[1][j] += sq_rnd(v.y);
      r1[2][j] += sq_rnd(v.z); r1[3][j] += sq_rnd(v.w);
    }
  }
  #pragma unroll
  for (int p = 0; p < 4; ++p) {
    const float t0 = ((r0[p][0] + r0[p][1]) + (r0[p][2] + r0[p][3])) +
                     ((r0[p][4] + r0[p][5]) + (r0[p][6] + r0[p][7]));
    const float t1 = ((r1[p][0] + r1[p][1]) + (r1[p][2] + r1[p][3])) +
                     ((r1[p][4] + r1[p][5]) + (r1[p][6] + r1[p][7]));
    z2[n0 + p] = t0 + t1;
  }
}

// Screening v3: f16 MFMA, block = 64 points x 1024 codes, pipelined (dbuf B,
// 2-deep reg staging, ONE barrier per phase).
// Epilogue threshold = min(wave-local RUNNING min across chunks, stale global) + W:
// every prefix min >= final min, so candidates form a superset of
// {codes within W of final screen min}; each wave adds only ~1-2 loose extras.
__global__ __launch_bounds__(256, 2) void vq_screen(
    const float* __restrict__ z, const _Float16* __restrict__ Ef,
    const float* __restrict__ e2, const float* __restrict__ z2,
    int* __restrict__ gcnt, unsigned short* __restrict__ gcand) {
  extern __shared__ __align__(16) char smem[];
  // [0,32768) A; [32768,65536) B dbuf; 65536 runminU[64]; 65792 cnt[64]; 66048 cand[64][16]
  unsigned* runminU = (unsigned*)(smem + 65536);
  int* cnt = (int*)(smem + 65792);
  unsigned short* cand = (unsigned short*)(smem + 66048);

  const int tid = threadIdx.x;
  const int blk = blockIdx.x;
  const int n0 = blk * 64;
  const int bb = blk >> 4;
  const int hw0 = (blk & 15) * 64;
  const float* zb = z + bb * 262144 + hw0;

  if (tid < 64) { runminU[tid] = 0x7F800000u; cnt[tid] = 0; }

  {  // A stage: convert z tile to f16, swizzled rows
    const int p = tid & 63, dh = tid >> 6;
    #pragma unroll
    for (int dq = 0; dq < 8; ++dq) {
      const int d0 = dh * 64 + dq * 8;
      f16x8 hv;
      #pragma unroll
      for (int j = 0; j < 8; ++j) hv[j] = (_Float16)zb[(d0 + j) * 1024 + p];
      *(f16x8*)&smem[p * 512 + ((d0 * 2) ^ ((p & 7) * 16))] = hv;
    }
  }

  const int l = tid & 63;
  const int ln = l & 15;
  const int q = l >> 4;
  const int wc = tid >> 6;        // wave: codes wc*64 .. +63 per chunk
  const int xr = (l & 7) * 16;
  const int bswz = (l & 3) * 16;

  float z2r[4][4];
  float rmrun[4][4];  // wave-local running min per point, across chunks
  #pragma unroll
  for (int fi = 0; fi < 4; ++fi)
    #pragma unroll
    for (int rg = 0; rg < 4; ++rg) {
      z2r[fi][rg] = z2[n0 + fi * 16 + q * 4 + rg];
      rmrun[fi][rg] = 3.4e38f;
    }

  f32x4 acc[4][4];
  #pragma unroll
  for (int fi = 0; fi < 4; ++fi)
    #pragma unroll
    for (int fj = 0; fj < 4; ++fj) acc[fi][fj] = (f32x4){0.f, 0.f, 0.f, 0.f};

  f16x8 stg[4];
  // prologue: tile 0 -> B0 ; tile 1 -> regs
  #pragma unroll
  for (int it = 0; it < 4; ++it) {
    const int c2 = it * 256 + tid;
    const int r = c2 >> 2, s = c2 & 3;
    stg[it] = *(const f16x8*)&Ef[r * 256 + (s ^ (r & 3)) * 8];  // t=0: cc=0,ph=0
  }
  #pragma unroll
  for (int it = 0; it < 4; ++it)
    *(f16x8*)&smem[32768 + it * 4096 + tid * 16] = stg[it];
  #pragma unroll
  for (int it = 0; it < 4; ++it) {
    const int c2 = it * 256 + tid;
    const int r = c2 >> 2, s = c2 & 3;
    stg[it] = *(const f16x8*)&Ef[r * 256 + 32 + (s ^ (r & 3)) * 8];  // t=1: ph=1
  }
  __syncthreads();

  for (int p = 0; p < 32; ++p) {
    char* Bw = smem + 32768 + (((p & 1) ^ 1) << 14);
    const char* Br = smem + 32768 + ((p & 1) << 14);
    if (p < 31) {  // ds_write tile p+1 (that buffer last read in phase p-1)
      #pragma unroll
      for (int it = 0; it < 4; ++it)
        *(f16x8*)&Bw[it * 4096 + tid * 16] = stg[it];
    }
    if (p < 30) {  // issue global loads for tile p+2
      const int t = p + 2;
      const int cct = t >> 3, pht = t & 7;
      #pragma unroll
      for (int it = 0; it < 4; ++it) {
        const int c2 = it * 256 + tid;
        const int r = c2 >> 2, s = c2 & 3;
        stg[it] = *(const f16x8*)&Ef[(cct * 256 + r) * 256 + pht * 32 +
                                     (s ^ (r & 3)) * 8];
      }
    }
    {  // compute phase p from Br
      const int ph = p & 7;
      f16x8 aF[4], bF[4];
      const int ab = (ph * 64 + q * 16) ^ xr;
      #pragma unroll
      for (int fi = 0; fi < 4; ++fi)
        aF[fi] = *(const f16x8*)&smem[(fi * 16 + ln) * 512 + ab];
      const int qb = (q * 16) ^ bswz;
      #pragma unroll
      for (int fj = 0; fj < 4; ++fj)
        bF[fj] = *(const f16x8*)&Br[(wc * 64 + fj * 16 + ln) * 64 + qb];
      #pragma unroll
      for (int fi = 0; fi < 4; ++fi)
        #pragma unroll
        for (int fj = 0; fj < 4; ++fj)
          acc[fi][fj] = __builtin_amdgcn_mfma_f32_16x16x32_f16(
              aF[fi], bF[fj], acc[fi][fj], 0, 0, 0);
    }
    if ((p & 7) == 7) {  // chunk epilogue (no barriers)
      const int cc = p >> 3;
      const int cbase = cc * 256 + wc * 64 + ln;
      float e2v[4];
      #pragma unroll
      for (int fj = 0; fj < 4; ++fj) e2v[fj] = e2[cbase + fj * 16];
      #pragma unroll
      for (int fi = 0; fi < 4; ++fi) {
        float sv[4][4];
        #pragma unroll
        for (int fj = 0; fj < 4; ++fj)
          #pragma unroll
          for (int rg = 0; rg < 4; ++rg)
            sv[fj][rg] = fmaf(-2.f, acc[fi][fj][rg], z2r[fi][rg] + e2v[fj]);
        #pragma unroll
        for (int rg = 0; rg < 4; ++rg) {
          float rm = fminf(fminf(sv[0][rg], sv[1][rg]), fminf(sv[2][rg], sv[3][rg]));
          rm = fminf(rm, __shfl_xor(rm, 1));
          rm = fminf(rm, __shfl_xor(rm, 2));
          rm = fminf(rm, __shfl_xor(rm, 4));
          rm = fminf(rm, __shfl_xor(rm, 8));
          rmrun[fi][rg] = fminf(rmrun[fi][rg], rm);  // running min across chunks
          const int row = fi * 16 + q * 4 + rg;
          if (ln == 0) atomicMin(&runminU[row], __float_as_uint(rm));
          const float g = __uint_as_float(runminU[row]);  // stale-ok (>= final min)
          const float thr = fminf(rmrun[fi][rg], g) + VQ_W;
          #pragma unroll
          for (int fj = 0; fj < 4; ++fj)
            if (sv[fj][rg] <= thr) {
              const int slot = atomicAdd(&cnt[row], 1);
              if (slot < 16)
                cand[row * 16 + slot] = (unsigned short)(cbase + fj * 16);
            }
        }
        #pragma unroll
        for (int fj = 0; fj < 4; ++fj) acc[fi][fj] = (f32x4){0.f, 0.f, 0.f, 0.f};
      }
    }
    __syncthreads();
  }

  if (tid < 64) gcnt[n0 + tid] = cnt[tid];
  {
    const int rr = tid >> 2, si = (tid & 3) * 4;
    *(uint2*)&gcand[(n0 + rr) * 16 + si] = *(const uint2*)&cand[rr * 16 + si];
  }
}

// Rescore (r6-verified): block = 64 points, z-tile in LDS, 4 threads/point split
// candidates; merge via LDS u64 atomicMin on (score_bits<<10)|k. Writes indices
// output directly.
__global__ __launch_bounds__(256) void vq_rescore(
    const float* __restrict__ z, const float* __restrict__ emb,
    const float* __restrict__ e2, const float* __restrict__ z2,
    const int* __restrict__ gcnt, const unsigned short* __restrict__ gcand,
    int* __restrict__ widx, float* __restrict__ out) {
  extern __shared__ __align__(16) char rsmem[];
  float* zt = (float*)rsmem;                                        // [64][257]
  unsigned long long* best = (unsigned long long*)(rsmem + 65792);  // [64]

  const int tid = threadIdx.x;
  const int w = tid >> 6;
  const int l = tid & 63;
  const int n0 = blockIdx.x << 6;
  const int bb = n0 >> 10, hw0 = n0 & 1023;
  const int n = n0 + l;

  const int c = gcnt[n];
  if (!__any(c >= 2)) {  // block-uniform: all waves see identical l-range
    if (w == 0) {
      const int v = gcand[n * 16];
      widx[n] = v;
      out[16777217 + n] = (float)v;
    }
    return;
  }

  {  // stage z tile
    const float* zb = z + bb * 262144 + hw0;
    #pragma unroll 8
    for (int it = 0; it < 64; ++it) {
      const int d = it * 4 + w;
      zt[l * 257 + d] = zb[d * 1024 + l];
    }
  }
  if (tid < 64) best[tid] = ~0ULL;
  __syncthreads();

  if (c >= 2) {
    const float z2n = z2[n];
    const float* zrow = &zt[l * 257];
    if (c <= 16) {
      for (int s = w; s < c; s += 4) {
        const int k = gcand[n * 16 + s];
        const float* ep = emb + k * 256;
        float a = 0.f;
        #pragma unroll 4
        for (int d = 0; d < 256; ++d) a = fmaf(zrow[d], ep[d], a);
        const float sv = fmaf(-2.f, a, z2n + e2[k]);
        const unsigned long long key =
            ((unsigned long long)__float_as_uint(sv) << 10) | (unsigned)k;
        atomicMin(&best[l], key);
      }
    } else {  // overflow fallback: exact full scan
      for (int k = w; k < 1024; k += 4) {
        const float* ep = emb + k * 256;
        float a = 0.f;
        #pragma unroll 4
        for (int d = 0; d < 256; ++d) a = fmaf(zrow[d], ep[d], a);
        const float sv = fmaf(-2.f, a, z2n + e2[k]);
        const unsigned long long key =
            ((unsigned long long)__float_as_uint(sv) << 10) | (unsigned)k;
        atomicMin(&best[l], key);
      }
    }
  }
  __syncthreads();
  if (tid < 64) {
    const int cc = gcnt[n0 + tid];
    const int v = (cc == 1) ? (int)gcand[(n0 + tid) * 16]
                            : (int)(best[tid] & 1023ULL);
    widx[n0 + tid] = v;
    out[16777217 + n0 + tid] = (float)v;
  }
}

// Output + loss (r3-verified). Gather 64 emb rows into LDS row-coalesced, then
// transpose-read (stride 260) + coalesced global write.
__global__ __launch_bounds__(256) void vq_out(const float* __restrict__ z,
                                              const float* __restrict__ emb,
                                              const int* __restrict__ widx,
                                              float* __restrict__ out,
                                              double* __restrict__ acc) {
  extern __shared__ float rows[];  // [64][260]
  const int tid = threadIdx.x;
  const int w = tid >> 6, l = tid & 63;
  const int n0 = blockIdx.x << 6;
  const int bb = n0 >> 10, hw0 = n0 & 1023;

  #pragma unroll 4
  for (int rr = 0; rr < 16; ++rr) {
    const int r = rr * 4 + w;
    const int idx = widx[n0 + r];
    const float4 ev = *(const float4*)&emb[idx * 256 + l * 4];
    *(float4*)&rows[r * 260 + l * 4] = ev;
  }
  __syncthreads();

  const int zofs = bb * 262144 + hw0 + l;
  const float* zp = z + zofs;
  float* op = out + zofs;
  double ls = 0.0;
  #pragma unroll 2
  for (int i16 = 0; i16 < 16; ++i16) {
    const int d4 = w * 64 + i16 * 4;
    const float4 q4 = *(const float4*)&rows[l * 260 + d4];
    #pragma unroll
    for (int e = 0; e < 4; ++e) {
      const int d = d4 + e;
      const float zv = zp[d * 1024];
      const float qv = ((const float*)&q4)[e];
      float df = qv - zv;
      asm volatile("" : "+v"(df));
      op[d * 1024] = zv + df;  // fl(z + fl(z_q - z))
      ls += (double)df * df;
    }
  }
  #pragma unroll
  for (int off = 32; off > 0; off >>= 1) ls += __shfl_down(ls, off);
  if (l == 0) atomicAdd(acc, ls);
}

__global__ void vq_fin(const double* __restrict__ acc, float* __restrict__ out) {
  if (threadIdx.x == 0)
    out[16777216] = (float)(1.25 * (*acc) * (1.0 / 16777216.0));
}

extern "C" void kernel_launch(void* const* d_in, const int* in_sizes, int n_in,
                              void* d_out, int out_size, void* d_ws, size_t ws_size,
                              hipStream_t stream) {
  const float* z = (const float*)d_in[0];
  const float* emb = (const float*)d_in[1];
  float* out = (float*)d_out;
  char* ws = (char*)d_ws;
  double* acc = (double*)(ws);
  int* widx = (int*)(ws + 64);
  float* e2 = (float*)(ws + 262208);
  float* z2 = (float*)(ws + 266304);
  int* gcnt = (int*)(ws + 528448);
  unsigned short* gcand = (unsigned short*)(ws + 790592);
  _Float16* Ef = (_Float16*)(ws + 2887744);

  hipFuncSetAttribute(reinterpret_cast<const void*>(vq_screen),
                      hipFuncAttributeMaxDynamicSharedMemorySize, SCR_LDS_BYTES);
  hipFuncSetAttribute(reinterpret_cast<const void*>(vq_rescore),
                      hipFuncAttributeMaxDynamicSharedMemorySize, RES_LDS_BYTES);
  hipFuncSetAttribute(reinterpret_cast<const void*>(vq_out),
                      hipFuncAttributeMaxDynamicSharedMemorySize, OUT_LDS_BYTES);

  hipMemsetAsync(ws, 0, 64, stream);
  vq_prep<<<1024, 256, 0, stream>>>(emb, Ef, e2);
  vq_z2<<<64, 256, 0, stream>>>(z, z2);
  vq_screen<<<1024, 256, SCR_LDS_BYTES, stream>>>(z, Ef, e2, z2, gcnt, gcand);
  vq_rescore<<<1024, 256, RES_LDS_BYTES, stream>>>(z, emb, e2, z2, gcnt, gcand,
                                                   widx, out);
  vq_out<<<1024, 256, OUT_LDS_BYTES, stream>>>(z, emb, widx, out, acc);
  vq_fin<<<1, 64, 0, stream>>>(acc, out);
}

// Round 9
// 339.915 us; speedup vs baseline: 2.0066x; 1.8426x over previous
//
#include <hip/hip_runtime.h>

// VectorQuantizer on MI355X — round 9: pipelined MFMA screen with barrier-synced
// exact prefix-min epilogue (restores cnt~1 candidate distribution of r6).
// z: (64,256,32,32) f32; emb: (1024,256) f32.
// out (f32): [0,16777216) z_q_out | [16777216] loss | [16777217,+65536) indices
//
// ws layout (bytes):
//   0        double   loss_acc                 (memset 0)
//   64       int      widx[65536]
//   262208   float    e2[1024]                 (numpy-pairwise fp32)
//   266304   float    z2[65536]                (numpy-pairwise fp32)
//   528448   int      gcnt[65536]
//   790592   ushort   gcand[65536*16]
//   2887744  _Float16 Ef[1024*256]             (f16 RNE copy of emb)

typedef _Float16 f16x8 __attribute__((ext_vector_type(8)));
typedef float f32x4 __attribute__((ext_vector_type(4)));

#define VQ_W 1.5e-3f
#define SCR_LDS_BYTES 68096
#define RES_LDS_BYTES (65792 + 512)
#define OUT_LDS_BYTES 66560

// fl32(v*v) with a barrier so the product cannot be contracted into a later add.
__device__ __forceinline__ float sq_rnd(float v) {
  float y = v * v;
  asm volatile("" : "+v"(y));
  return y;
}

// numpy pairwise_sum over 256 fp32 squared terms (8-accumulator blocks of 128).
__device__ float np_pw256_sq(const float* base, int stride) {
  float tot0, tot1;
  {
    const float* a = base;
    float r[8];
    #pragma unroll
    for (int j = 0; j < 8; ++j) r[j] = sq_rnd(a[j * stride]);
    #pragma unroll 1
    for (int i = 8; i < 128; i += 8) {
      #pragma unroll
      for (int j = 0; j < 8; ++j) r[j] += sq_rnd(a[(i + j) * stride]);
    }
    tot0 = ((r[0] + r[1]) + (r[2] + r[3])) + ((r[4] + r[5]) + (r[6] + r[7]));
  }
  {
    const float* a = base + 128 * stride;
    float r[8];
    #pragma unroll
    for (int j = 0; j < 8; ++j) r[j] = sq_rnd(a[j * stride]);
    #pragma unroll 1
    for (int i = 8; i < 128; i += 8) {
      #pragma unroll
      for (int j = 0; j < 8; ++j) r[j] += sq_rnd(a[(i + j) * stride]);
    }
    tot1 = ((r[0] + r[1]) + (r[2] + r[3])) + ((r[4] + r[5]) + (r[6] + r[7]));
  }
  return tot0 + tot1;
}

__global__ __launch_bounds__(256) void vq_prep(const float* __restrict__ emb,
                                               _Float16* __restrict__ Ef,
                                               float* __restrict__ e2) {
  const int g = blockIdx.x * 256 + threadIdx.x;  // 0..262143
  Ef[g] = (_Float16)emb[g];                      // RNE v_cvt_f16_f32
  if (g < 1024) e2[g] = np_pw256_sq(emb + g * 256, 1);
}

// |z|^2 per point, numpy-pairwise. 4 points/thread via float4 along hw. (r3-verified)
__global__ __launch_bounds__(256) void vq_z2(const float* __restrict__ z,
                                             float* __restrict__ z2) {
  const int t4 = blockIdx.x * 256 + threadIdx.x;  // 0..16383
  const int n0 = t4 * 4;
  const int bb = n0 >> 10, hw = n0 & 1023;
  const float* zp = z + bb * 262144 + hw;
  float r0[4][8], r1[4][8];
  #pragma unroll
  for (int p = 0; p < 4; ++p)
    #pragma unroll
    for (int j = 0; j < 8; ++j) { r0[p][j] = 0.f; r1[p][j] = 0.f; }
  #pragma unroll 1
  for (int d8 = 0; d8 < 128; d8 += 8) {
    #pragma unroll
    for (int j = 0; j < 8; ++j) {
      const float4 v = *(const float4*)&zp[(d8 + j) * 1024];
      r0[0][j] += sq_rnd(v.x); r0[1][j] += sq_rnd(v.y);
      r0[2][j] += sq_rnd(v.z); r0[3][j] += sq_rnd(v.w);
    }
  }
  #pragma unroll 1
  for (int d8 = 128; d8 < 256; d8 += 8) {
    #pragma unroll
    for (int j = 0; j < 8; ++j) {
      const float4 v = *(const float4*)&zp[(d8 + j) * 1024];
      r1[0][j] += sq_rnd(v.x); r1[1][j] += sq_rnd(v.y);
      r1[2][j] += sq_rnd(v.z); r1[3][j] += sq_rnd(v.w);
    }
  }
  #pragma unroll
  for (int p = 0; p < 4; ++p) {
    const float t0 = ((r0[p][0] + r0[p][1]) + (r0[p][2] + r0[p][3])) +
                     ((r0[p][4] + r0[p][5]) + (r0[p][6] + r0[p][7]));
    const float t1 = ((r1[p][0] + r1[p][1]) + (r1[p][2] + r1[p][3])) +
                     ((r1[p][4] + r1[p][5]) + (r1[p][6] + r1[p][7]));
    z2[n0 + p] = t0 + t1;
  }
}

// Screening v4: f16 MFMA, block = 64 points x 1024 codes, pipelined (dbuf B,
// 2-deep reg staging, ONE barrier per phase). Chunk epilogue is barrier-synced:
// (1) wave mins -> atomicMin(runminU); (2) __syncthreads(); (3) recompute sv
// from live acc, collect with thr = true_prefix_min + W. Superset guarantee:
// prefix min >= final min, and |screen - exact| <= W/2-ish (f16 bound), so the
// exact argmin is always collected; typical cnt == 1.
__global__ __launch_bounds__(256, 2) void vq_screen(
    const float* __restrict__ z, const _Float16* __restrict__ Ef,
    const float* __restrict__ e2, const float* __restrict__ z2,
    int* __restrict__ gcnt, unsigned short* __restrict__ gcand) {
  extern __shared__ __align__(16) char smem[];
  // [0,32768) A; [32768,65536) B dbuf; 65536 runminU[64]; 65792 cnt[64]; 66048 cand[64][16]
  unsigned* runminU = (unsigned*)(smem + 65536);
  int* cnt = (int*)(smem + 65792);
  unsigned short* cand = (unsigned short*)(smem + 66048);

  const int tid = threadIdx.x;
  const int blk = blockIdx.x;
  const int n0 = blk * 64;
  const int bb = blk >> 4;
  const int hw0 = (blk & 15) * 64;
  const float* zb = z + bb * 262144 + hw0;

  if (tid < 64) { runminU[tid] = 0x7F800000u; cnt[tid] = 0; }

  {  // A stage: convert z tile to f16, swizzled rows
    const int p = tid & 63, dh = tid >> 6;
    #pragma unroll
    for (int dq = 0; dq < 8; ++dq) {
      const int d0 = dh * 64 + dq * 8;
      f16x8 hv;
      #pragma unroll
      for (int j = 0; j < 8; ++j) hv[j] = (_Float16)zb[(d0 + j) * 1024 + p];
      *(f16x8*)&smem[p * 512 + ((d0 * 2) ^ ((p & 7) * 16))] = hv;
    }
  }

  const int l = tid & 63;
  const int ln = l & 15;
  const int q = l >> 4;
  const int wc = tid >> 6;        // wave: codes wc*64 .. +63 per chunk
  const int xr = (l & 7) * 16;
  const int bswz = (l & 3) * 16;

  float z2r[4][4];
  #pragma unroll
  for (int fi = 0; fi < 4; ++fi)
    #pragma unroll
    for (int rg = 0; rg < 4; ++rg)
      z2r[fi][rg] = z2[n0 + fi * 16 + q * 4 + rg];

  f32x4 acc[4][4];
  #pragma unroll
  for (int fi = 0; fi < 4; ++fi)
    #pragma unroll
    for (int fj = 0; fj < 4; ++fj) acc[fi][fj] = (f32x4){0.f, 0.f, 0.f, 0.f};

  f16x8 stg[4];
  // prologue: tile 0 -> B0 ; tile 1 -> regs
  #pragma unroll
  for (int it = 0; it < 4; ++it) {
    const int c2 = it * 256 + tid;
    const int r = c2 >> 2, s = c2 & 3;
    stg[it] = *(const f16x8*)&Ef[r * 256 + (s ^ (r & 3)) * 8];  // t=0: cc=0,ph=0
  }
  #pragma unroll
  for (int it = 0; it < 4; ++it)
    *(f16x8*)&smem[32768 + it * 4096 + tid * 16] = stg[it];
  #pragma unroll
  for (int it = 0; it < 4; ++it) {
    const int c2 = it * 256 + tid;
    const int r = c2 >> 2, s = c2 & 3;
    stg[it] = *(const f16x8*)&Ef[r * 256 + 32 + (s ^ (r & 3)) * 8];  // t=1: ph=1
  }
  __syncthreads();

  for (int p = 0; p < 32; ++p) {
    char* Bw = smem + 32768 + (((p & 1) ^ 1) << 14);
    const char* Br = smem + 32768 + ((p & 1) << 14);
    if (p < 31) {  // ds_write tile p+1 (that buffer last read in phase p-1)
      #pragma unroll
      for (int it = 0; it < 4; ++it)
        *(f16x8*)&Bw[it * 4096 + tid * 16] = stg[it];
    }
    if (p < 30) {  // issue global loads for tile p+2
      const int t = p + 2;
      const int cct = t >> 3, pht = t & 7;
      #pragma unroll
      for (int it = 0; it < 4; ++it) {
        const int c2 = it * 256 + tid;
        const int r = c2 >> 2, s = c2 & 3;
        stg[it] = *(const f16x8*)&Ef[(cct * 256 + r) * 256 + pht * 32 +
                                     (s ^ (r & 3)) * 8];
      }
    }
    {  // compute phase p from Br
      const int ph = p & 7;
      f16x8 aF[4], bF[4];
      const int ab = (ph * 64 + q * 16) ^ xr;
      #pragma unroll
      for (int fi = 0; fi < 4; ++fi)
        aF[fi] = *(const f16x8*)&smem[(fi * 16 + ln) * 512 + ab];
      const int qb = (q * 16) ^ bswz;
      #pragma unroll
      for (int fj = 0; fj < 4; ++fj)
        bF[fj] = *(const f16x8*)&Br[(wc * 64 + fj * 16 + ln) * 64 + qb];
      #pragma unroll
      for (int fi = 0; fi < 4; ++fi)
        #pragma unroll
        for (int fj = 0; fj < 4; ++fj)
          acc[fi][fj] = __builtin_amdgcn_mfma_f32_16x16x32_f16(
              aF[fi], bF[fj], acc[fi][fj], 0, 0, 0);
    }
    if ((p & 7) == 7) {  // chunk epilogue: exact prefix-min via one barrier
      const int cc = p >> 3;
      const int cbase = cc * 256 + wc * 64 + ln;
      float e2v[4];
      #pragma unroll
      for (int fj = 0; fj < 4; ++fj) e2v[fj] = e2[cbase + fj * 16];
      // Phase 1: wave-local mins -> atomicMin into runminU
      #pragma unroll
      for (int fi = 0; fi < 4; ++fi) {
        #pragma unroll
        for (int rg = 0; rg < 4; ++rg) {
          float rm = 3.4e38f;
          #pragma unroll
          for (int fj = 0; fj < 4; ++fj)
            rm = fminf(rm, fmaf(-2.f, acc[fi][fj][rg], z2r[fi][rg] + e2v[fj]));
          rm = fminf(rm, __shfl_xor(rm, 1));
          rm = fminf(rm, __shfl_xor(rm, 2));
          rm = fminf(rm, __shfl_xor(rm, 4));
          rm = fminf(rm, __shfl_xor(rm, 8));
          if (ln == 0)
            atomicMin(&runminU[fi * 16 + q * 4 + rg], __float_as_uint(rm));
        }
      }
      __syncthreads();  // runminU now = true min over ALL codes up to chunk cc
      // Phase 2: collect candidates against the exact prefix min
      #pragma unroll
      for (int fi = 0; fi < 4; ++fi) {
        #pragma unroll
        for (int rg = 0; rg < 4; ++rg) {
          const int row = fi * 16 + q * 4 + rg;
          const float thr = __uint_as_float(runminU[row]) + VQ_W;
          #pragma unroll
          for (int fj = 0; fj < 4; ++fj) {
            const float sv = fmaf(-2.f, acc[fi][fj][rg], z2r[fi][rg] + e2v[fj]);
            if (sv <= thr) {
              const int slot = atomicAdd(&cnt[row], 1);
              if (slot < 16)
                cand[row * 16 + slot] = (unsigned short)(cbase + fj * 16);
            }
          }
        }
        #pragma unroll
        for (int fj = 0; fj < 4; ++fj) acc[fi][fj] = (f32x4){0.f, 0.f, 0.f, 0.f};
      }
    }
    __syncthreads();
  }

  if (tid < 64) gcnt[n0 + tid] = cnt[tid];
  {
    const int rr = tid >> 2, si = (tid & 3) * 4;
    *(uint2*)&gcand[(n0 + rr) * 16 + si] = *(const uint2*)&cand[rr * 16 + si];
  }
}

// Rescore (r6-verified): block = 64 points, z-tile in LDS, 4 threads/point split
// candidates; merge via LDS u64 atomicMin on (score_bits<<10)|k. Writes indices
// output directly.
__global__ __launch_bounds__(256) void vq_rescore(
    const float* __restrict__ z, const float* __restrict__ emb,
    const float* __restrict__ e2, const float* __restrict__ z2,
    const int* __restrict__ gcnt, const unsigned short* __restrict__ gcand,
    int* __restrict__ widx, float* __restrict__ out) {
  extern __shared__ __align__(16) char rsmem[];
  float* zt = (float*)rsmem;                                        // [64][257]
  unsigned long long* best = (unsigned long long*)(rsmem + 65792);  // [64]

  const int tid = threadIdx.x;
  const int w = tid >> 6;
  const int l = tid & 63;
  const int n0 = blockIdx.x << 6;
  const int bb = n0 >> 10, hw0 = n0 & 1023;
  const int n = n0 + l;

  const int c = gcnt[n];
  if (!__any(c >= 2)) {  // block-uniform: all waves see identical l-range
    if (w == 0) {
      const int v = gcand[n * 16];
      widx[n] = v;
      out[16777217 + n] = (float)v;
    }
    return;
  }

  {  // stage z tile
    const float* zb = z + bb * 262144 + hw0;
    #pragma unroll 8
    for (int it = 0; it < 64; ++it) {
      const int d = it * 4 + w;
      zt[l * 257 + d] = zb[d * 1024 + l];
    }
  }
  if (tid < 64) best[tid] = ~0ULL;
  __syncthreads();

  if (c >= 2) {
    const float z2n = z2[n];
    const float* zrow = &zt[l * 257];
    if (c <= 16) {
      for (int s = w; s < c; s += 4) {
        const int k = gcand[n * 16 + s];
        const float* ep = emb + k * 256;
        float a = 0.f;
        #pragma unroll 4
        for (int d = 0; d < 256; ++d) a = fmaf(zrow[d], ep[d], a);
        const float sv = fmaf(-2.f, a, z2n + e2[k]);
        const unsigned long long key =
            ((unsigned long long)__float_as_uint(sv) << 10) | (unsigned)k;
        atomicMin(&best[l], key);
      }
    } else {  // overflow fallback: exact full scan
      for (int k = w; k < 1024; k += 4) {
        const float* ep = emb + k * 256;
        float a = 0.f;
        #pragma unroll 4
        for (int d = 0; d < 256; ++d) a = fmaf(zrow[d], ep[d], a);
        const float sv = fmaf(-2.f, a, z2n + e2[k]);
        const unsigned long long key =
            ((unsigned long long)__float_as_uint(sv) << 10) | (unsigned)k;
        atomicMin(&best[l], key);
      }
    }
  }
  __syncthreads();
  if (tid < 64) {
    const int cc = gcnt[n0 + tid];
    const int v = (cc == 1) ? (int)gcand[(n0 + tid) * 16]
                            : (int)(best[tid] & 1023ULL);
    widx[n0 + tid] = v;
    out[16777217 + n0 + tid] = (float)v;
  }
}

// Output + loss (r3-verified). Gather 64 emb rows into LDS row-coalesced, then
// transpose-read (stride 260) + coalesced global write.
__global__ __launch_bounds__(256) void vq_out(const float* __restrict__ z,
                                              const float* __restrict__ emb,
                                              const int* __restrict__ widx,
                                              float* __restrict__ out,
                                              double* __restrict__ acc) {
  extern __shared__ float rows[];  // [64][260]
  const int tid = threadIdx.x;
  const int w = tid >> 6, l = tid & 63;
  const int n0 = blockIdx.x << 6;
  const int bb = n0 >> 10, hw0 = n0 & 1023;

  #pragma unroll 4
  for (int rr = 0; rr < 16; ++rr) {
    const int r = rr * 4 + w;
    const int idx = widx[n0 + r];
    const float4 ev = *(const float4*)&emb[idx * 256 + l * 4];
    *(float4*)&rows[r * 260 + l * 4] = ev;
  }
  __syncthreads();

  const int zofs = bb * 262144 + hw0 + l;
  const float* zp = z + zofs;
  float* op = out + zofs;
  double ls = 0.0;
  #pragma unroll 2
  for (int i16 = 0; i16 < 16; ++i16) {
    const int d4 = w * 64 + i16 * 4;
    const float4 q4 = *(const float4*)&rows[l * 260 + d4];
    #pragma unroll
    for (int e = 0; e < 4; ++e) {
      const int d = d4 + e;
      const float zv = zp[d * 1024];
      const float qv = ((const float*)&q4)[e];
      float df = qv - zv;
      asm volatile("" : "+v"(df));
      op[d * 1024] = zv + df;  // fl(z + fl(z_q - z))
      ls += (double)df * df;
    }
  }
  #pragma unroll
  for (int off = 32; off > 0; off >>= 1) ls += __shfl_down(ls, off);
  if (l == 0) atomicAdd(acc, ls);
}

__global__ void vq_fin(const double* __restrict__ acc, float* __restrict__ out) {
  if (threadIdx.x == 0)
    out[16777216] = (float)(1.25 * (*acc) * (1.0 / 16777216.0));
}

extern "C" void kernel_launch(void* const* d_in, const int* in_sizes, int n_in,
                              void* d_out, int out_size, void* d_ws, size_t ws_size,
                              hipStream_t stream) {
  const float* z = (const float*)d_in[0];
  const float* emb = (const float*)d_in[1];
  float* out = (float*)d_out;
  char* ws = (char*)d_ws;
  double* acc = (double*)(ws);
  int* widx = (int*)(ws + 64);
  float* e2 = (float*)(ws + 262208);
  float* z2 = (float*)(ws + 266304);
  int* gcnt = (int*)(ws + 528448);
  unsigned short* gcand = (unsigned short*)(ws + 790592);
  _Float16* Ef = (_Float16*)(ws + 2887744);

  hipFuncSetAttribute(reinterpret_cast<const void*>(vq_screen),
                      hipFuncAttributeMaxDynamicSharedMemorySize, SCR_LDS_BYTES);
  hipFuncSetAttribute(reinterpret_cast<const void*>(vq_rescore),
                      hipFuncAttributeMaxDynamicSharedMemorySize, RES_LDS_BYTES);
  hipFuncSetAttribute(reinterpret_cast<const void*>(vq_out),
                      hipFuncAttributeMaxDynamicSharedMemorySize, OUT_LDS_BYTES);

  hipMemsetAsync(ws, 0, 64, stream);
  vq_prep<<<1024, 256, 0, stream>>>(emb, Ef, e2);
  vq_z2<<<64, 256, 0, stream>>>(z, z2);
  vq_screen<<<1024, 256, SCR_LDS_BYTES, stream>>>(z, Ef, e2, z2, gcnt, gcand);
  vq_rescore<<<1024, 256, RES_LDS_BYTES, stream>>>(z, emb, e2, z2, gcnt, gcand,
                                                   widx, out);
  vq_out<<<1024, 256, OUT_LDS_BYTES, stream>>>(z, emb, widx, out, acc);
  vq_fin<<<1, 64, 0, stream>>>(acc, out);
}

// Round 10
// 330.635 us; speedup vs baseline: 2.0629x; 1.0281x over previous
//
#include <hip/hip_runtime.h>

// VectorQuantizer on MI355X — round 10: vq_z2 grid fix (1 pt/thread, 256 blocks).
// z: (64,256,32,32) f32; emb: (1024,256) f32.
// out (f32): [0,16777216) z_q_out | [16777216] loss | [16777217,+65536) indices
//
// ws layout (bytes):
//   0        double   loss_acc                 (memset 0)
//   64       int      widx[65536]
//   262208   float    e2[1024]                 (numpy-pairwise fp32)
//   266304   float    z2[65536]                (numpy-pairwise fp32)
//   528448   int      gcnt[65536]
//   790592   ushort   gcand[65536*16]
//   2887744  _Float16 Ef[1024*256]             (f16 RNE copy of emb)

typedef _Float16 f16x8 __attribute__((ext_vector_type(8)));
typedef float f32x4 __attribute__((ext_vector_type(4)));

#define VQ_W 1.5e-3f
#define SCR_LDS_BYTES 68096
#define RES_LDS_BYTES (65792 + 512)
#define OUT_LDS_BYTES 66560

// fl32(v*v) with a barrier so the product cannot be contracted into a later add.
__device__ __forceinline__ float sq_rnd(float v) {
  float y = v * v;
  asm volatile("" : "+v"(y));
  return y;
}

// numpy pairwise_sum over 256 fp32 squared terms (8-accumulator blocks of 128).
__device__ float np_pw256_sq(const float* base, int stride) {
  float tot0, tot1;
  {
    const float* a = base;
    float r[8];
    #pragma unroll
    for (int j = 0; j < 8; ++j) r[j] = sq_rnd(a[j * stride]);
    #pragma unroll 1
    for (int i = 8; i < 128; i += 8) {
      #pragma unroll
      for (int j = 0; j < 8; ++j) r[j] += sq_rnd(a[(i + j) * stride]);
    }
    tot0 = ((r[0] + r[1]) + (r[2] + r[3])) + ((r[4] + r[5]) + (r[6] + r[7]));
  }
  {
    const float* a = base + 128 * stride;
    float r[8];
    #pragma unroll
    for (int j = 0; j < 8; ++j) r[j] = sq_rnd(a[j * stride]);
    #pragma unroll 1
    for (int i = 8; i < 128; i += 8) {
      #pragma unroll
      for (int j = 0; j < 8; ++j) r[j] += sq_rnd(a[(i + j) * stride]);
    }
    tot1 = ((r[0] + r[1]) + (r[2] + r[3])) + ((r[4] + r[5]) + (r[6] + r[7]));
  }
  return tot0 + tot1;
}

__global__ __launch_bounds__(256) void vq_prep(const float* __restrict__ emb,
                                               _Float16* __restrict__ Ef,
                                               float* __restrict__ e2) {
  const int g = blockIdx.x * 256 + threadIdx.x;  // 0..262143
  Ef[g] = (_Float16)emb[g];                      // RNE v_cvt_f16_f32
  if (g < 1024) e2[g] = np_pw256_sq(emb + g * 256, 1);
}

// |z|^2 per point, numpy-pairwise, v2: ONE point per thread, 256 blocks (full
// CU coverage). Wave lanes = consecutive hw -> coalesced 256B per d. FP order
// identical to np_pw256_sq (chains sequential in i; combine trees unchanged).
__global__ __launch_bounds__(256) void vq_z2(const float* __restrict__ z,
                                             float* __restrict__ z2) {
  const int n = blockIdx.x * 256 + threadIdx.x;  // 0..65535
  const int bb = n >> 10, hw = n & 1023;
  const float* zp = z + bb * 262144 + hw;
  float r[8];
  float tot0, tot1;
  #pragma unroll
  for (int j = 0; j < 8; ++j) r[j] = sq_rnd(zp[j * 1024]);
  #pragma unroll 5
  for (int i = 8; i < 128; i += 8) {
    #pragma unroll
    for (int j = 0; j < 8; ++j) r[j] += sq_rnd(zp[(i + j) * 1024]);
  }
  tot0 = ((r[0] + r[1]) + (r[2] + r[3])) + ((r[4] + r[5]) + (r[6] + r[7]));
  #pragma unroll
  for (int j = 0; j < 8; ++j) r[j] = sq_rnd(zp[(128 + j) * 1024]);
  #pragma unroll 5
  for (int i = 136; i < 256; i += 8) {
    #pragma unroll
    for (int j = 0; j < 8; ++j) r[j] += sq_rnd(zp[(i + j) * 1024]);
  }
  tot1 = ((r[0] + r[1]) + (r[2] + r[3])) + ((r[4] + r[5]) + (r[6] + r[7]));
  z2[n] = tot0 + tot1;
}

// Screening v4 (r9-verified): f16 MFMA, block = 64 points x 1024 codes, pipelined
// (dbuf B, 2-deep reg staging, ONE barrier per phase). Chunk epilogue barrier-
// synced: wave mins -> atomicMin(runminU); barrier; collect with
// thr = true_prefix_min + W (superset of final-min window; typical cnt == 1).
__global__ __launch_bounds__(256, 2) void vq_screen(
    const float* __restrict__ z, const _Float16* __restrict__ Ef,
    const float* __restrict__ e2, const float* __restrict__ z2,
    int* __restrict__ gcnt, unsigned short* __restrict__ gcand) {
  extern __shared__ __align__(16) char smem[];
  // [0,32768) A; [32768,65536) B dbuf; 65536 runminU[64]; 65792 cnt[64]; 66048 cand[64][16]
  unsigned* runminU = (unsigned*)(smem + 65536);
  int* cnt = (int*)(smem + 65792);
  unsigned short* cand = (unsigned short*)(smem + 66048);

  const int tid = threadIdx.x;
  const int blk = blockIdx.x;
  const int n0 = blk * 64;
  const int bb = blk >> 4;
  const int hw0 = (blk & 15) * 64;
  const float* zb = z + bb * 262144 + hw0;

  if (tid < 64) { runminU[tid] = 0x7F800000u; cnt[tid] = 0; }

  {  // A stage: convert z tile to f16, swizzled rows
    const int p = tid & 63, dh = tid >> 6;
    #pragma unroll
    for (int dq = 0; dq < 8; ++dq) {
      const int d0 = dh * 64 + dq * 8;
      f16x8 hv;
      #pragma unroll
      for (int j = 0; j < 8; ++j) hv[j] = (_Float16)zb[(d0 + j) * 1024 + p];
      *(f16x8*)&smem[p * 512 + ((d0 * 2) ^ ((p & 7) * 16))] = hv;
    }
  }

  const int l = tid & 63;
  const int ln = l & 15;
  const int q = l >> 4;
  const int wc = tid >> 6;        // wave: codes wc*64 .. +63 per chunk
  const int xr = (l & 7) * 16;
  const int bswz = (l & 3) * 16;

  float z2r[4][4];
  #pragma unroll
  for (int fi = 0; fi < 4; ++fi)
    #pragma unroll
    for (int rg = 0; rg < 4; ++rg)
      z2r[fi][rg] = z2[n0 + fi * 16 + q * 4 + rg];

  f32x4 acc[4][4];
  #pragma unroll
  for (int fi = 0; fi < 4; ++fi)
    #pragma unroll
    for (int fj = 0; fj < 4; ++fj) acc[fi][fj] = (f32x4){0.f, 0.f, 0.f, 0.f};

  f16x8 stg[4];
  // prologue: tile 0 -> B0 ; tile 1 -> regs
  #pragma unroll
  for (int it = 0; it < 4; ++it) {
    const int c2 = it * 256 + tid;
    const int r = c2 >> 2, s = c2 & 3;
    stg[it] = *(const f16x8*)&Ef[r * 256 + (s ^ (r & 3)) * 8];  // t=0: cc=0,ph=0
  }
  #pragma unroll
  for (int it = 0; it < 4; ++it)
    *(f16x8*)&smem[32768 + it * 4096 + tid * 16] = stg[it];
  #pragma unroll
  for (int it = 0; it < 4; ++it) {
    const int c2 = it * 256 + tid;
    const int r = c2 >> 2, s = c2 & 3;
    stg[it] = *(const f16x8*)&Ef[r * 256 + 32 + (s ^ (r & 3)) * 8];  // t=1: ph=1
  }
  __syncthreads();

  for (int p = 0; p < 32; ++p) {
    char* Bw = smem + 32768 + (((p & 1) ^ 1) << 14);
    const char* Br = smem + 32768 + ((p & 1) << 14);
    if (p < 31) {  // ds_write tile p+1 (that buffer last read in phase p-1)
      #pragma unroll
      for (int it = 0; it < 4; ++it)
        *(f16x8*)&Bw[it * 4096 + tid * 16] = stg[it];
    }
    if (p < 30) {  // issue global loads for tile p+2
      const int t = p + 2;
      const int cct = t >> 3, pht = t & 7;
      #pragma unroll
      for (int it = 0; it < 4; ++it) {
        const int c2 = it * 256 + tid;
        const int r = c2 >> 2, s = c2 & 3;
        stg[it] = *(const f16x8*)&Ef[(cct * 256 + r) * 256 + pht * 32 +
                                     (s ^ (r & 3)) * 8];
      }
    }
    {  // compute phase p from Br
      const int ph = p & 7;
      f16x8 aF[4], bF[4];
      const int ab = (ph * 64 + q * 16) ^ xr;
      #pragma unroll
      for (int fi = 0; fi < 4; ++fi)
        aF[fi] = *(const f16x8*)&smem[(fi * 16 + ln) * 512 + ab];
      const int qb = (q * 16) ^ bswz;
      #pragma unroll
      for (int fj = 0; fj < 4; ++fj)
        bF[fj] = *(const f16x8*)&Br[(wc * 64 + fj * 16 + ln) * 64 + qb];
      #pragma unroll
      for (int fi = 0; fi < 4; ++fi)
        #pragma unroll
        for (int fj = 0; fj < 4; ++fj)
          acc[fi][fj] = __builtin_amdgcn_mfma_f32_16x16x32_f16(
              aF[fi], bF[fj], acc[fi][fj], 0, 0, 0);
    }
    if ((p & 7) == 7) {  // chunk epilogue: exact prefix-min via one barrier
      const int cc = p >> 3;
      const int cbase = cc * 256 + wc * 64 + ln;
      float e2v[4];
      #pragma unroll
      for (int fj = 0; fj < 4; ++fj) e2v[fj] = e2[cbase + fj * 16];
      // Phase 1: wave-local mins -> atomicMin into runminU
      #pragma unroll
      for (int fi = 0; fi < 4; ++fi) {
        #pragma unroll
        for (int rg = 0; rg < 4; ++rg) {
          float rm = 3.4e38f;
          #pragma unroll
          for (int fj = 0; fj < 4; ++fj)
            rm = fminf(rm, fmaf(-2.f, acc[fi][fj][rg], z2r[fi][rg] + e2v[fj]));
          rm = fminf(rm, __shfl_xor(rm, 1));
          rm = fminf(rm, __shfl_xor(rm, 2));
          rm = fminf(rm, __shfl_xor(rm, 4));
          rm = fminf(rm, __shfl_xor(rm, 8));
          if (ln == 0)
            atomicMin(&runminU[fi * 16 + q * 4 + rg], __float_as_uint(rm));
        }
      }
      __syncthreads();  // runminU now = true min over ALL codes up to chunk cc
      // Phase 2: collect candidates against the exact prefix min
      #pragma unroll
      for (int fi = 0; fi < 4; ++fi) {
        #pragma unroll
        for (int rg = 0; rg < 4; ++rg) {
          const int row = fi * 16 + q * 4 + rg;
          const float thr = __uint_as_float(runminU[row]) + VQ_W;
          #pragma unroll
          for (int fj = 0; fj < 4; ++fj) {
            const float sv = fmaf(-2.f, acc[fi][fj][rg], z2r[fi][rg] + e2v[fj]);
            if (sv <= thr) {
              const int slot = atomicAdd(&cnt[row], 1);
              if (slot < 16)
                cand[row * 16 + slot] = (unsigned short)(cbase + fj * 16);
            }
          }
        }
        #pragma unroll
        for (int fj = 0; fj < 4; ++fj) acc[fi][fj] = (f32x4){0.f, 0.f, 0.f, 0.f};
      }
    }
    __syncthreads();
  }

  if (tid < 64) gcnt[n0 + tid] = cnt[tid];
  {
    const int rr = tid >> 2, si = (tid & 3) * 4;
    *(uint2*)&gcand[(n0 + rr) * 16 + si] = *(const uint2*)&cand[rr * 16 + si];
  }
}

// Rescore (r6-verified): block = 64 points, z-tile in LDS, 4 threads/point split
// candidates; merge via LDS u64 atomicMin on (score_bits<<10)|k. Writes indices
// output directly.
__global__ __launch_bounds__(256) void vq_rescore(
    const float* __restrict__ z, const float* __restrict__ emb,
    const float* __restrict__ e2, const float* __restrict__ z2,
    const int* __restrict__ gcnt, const unsigned short* __restrict__ gcand,
    int* __restrict__ widx, float* __restrict__ out) {
  extern __shared__ __align__(16) char rsmem[];
  float* zt = (float*)rsmem;                                        // [64][257]
  unsigned long long* best = (unsigned long long*)(rsmem + 65792);  // [64]

  const int tid = threadIdx.x;
  const int w = tid >> 6;
  const int l = tid & 63;
  const int n0 = blockIdx.x << 6;
  const int bb = n0 >> 10, hw0 = n0 & 1023;
  const int n = n0 + l;

  const int c = gcnt[n];
  if (!__any(c >= 2)) {  // block-uniform: all waves see identical l-range
    if (w == 0) {
      const int v = gcand[n * 16];
      widx[n] = v;
      out[16777217 + n] = (float)v;
    }
    return;
  }

  {  // stage z tile
    const float* zb = z + bb * 262144 + hw0;
    #pragma unroll 8
    for (int it = 0; it < 64; ++it) {
      const int d = it * 4 + w;
      zt[l * 257 + d] = zb[d * 1024 + l];
    }
  }
  if (tid < 64) best[tid] = ~0ULL;
  __syncthreads();

  if (c >= 2) {
    const float z2n = z2[n];
    const float* zrow = &zt[l * 257];
    if (c <= 16) {
      for (int s = w; s < c; s += 4) {
        const int k = gcand[n * 16 + s];
        const float* ep = emb + k * 256;
        float a = 0.f;
        #pragma unroll 4
        for (int d = 0; d < 256; ++d) a = fmaf(zrow[d], ep[d], a);
        const float sv = fmaf(-2.f, a, z2n + e2[k]);
        const unsigned long long key =
            ((unsigned long long)__float_as_uint(sv) << 10) | (unsigned)k;
        atomicMin(&best[l], key);
      }
    } else {  // overflow fallback: exact full scan
      for (int k = w; k < 1024; k += 4) {
        const float* ep = emb + k * 256;
        float a = 0.f;
        #pragma unroll 4
        for (int d = 0; d < 256; ++d) a = fmaf(zrow[d], ep[d], a);
        const float sv = fmaf(-2.f, a, z2n + e2[k]);
        const unsigned long long key =
            ((unsigned long long)__float_as_uint(sv) << 10) | (unsigned)k;
        atomicMin(&best[l], key);
      }
    }
  }
  __syncthreads();
  if (tid < 64) {
    const int cc = gcnt[n0 + tid];
    const int v = (cc == 1) ? (int)gcand[(n0 + tid) * 16]
                            : (int)(best[tid] & 1023ULL);
    widx[n0 + tid] = v;
    out[16777217 + n0 + tid] = (float)v;
  }
}

// Output + loss (r3-verified). Gather 64 emb rows into LDS row-coalesced, then
// transpose-read (stride 260) + coalesced global write.
__global__ __launch_bounds__(256) void vq_out(const float* __restrict__ z,
                                              const float* __restrict__ emb,
                                              const int* __restrict__ widx,
                                              float* __restrict__ out,
                                              double* __restrict__ acc) {
  extern __shared__ float rows[];  // [64][260]
  const int tid = threadIdx.x;
  const int w = tid >> 6, l = tid & 63;
  const int n0 = blockIdx.x << 6;
  const int bb = n0 >> 10, hw0 = n0 & 1023;

  #pragma unroll 4
  for (int rr = 0; rr < 16; ++rr) {
    const int r = rr * 4 + w;
    const int idx = widx[n0 + r];
    const float4 ev = *(const float4*)&emb[idx * 256 + l * 4];
    *(float4*)&rows[r * 260 + l * 4] = ev;
  }
  __syncthreads();

  const int zofs = bb * 262144 + hw0 + l;
  const float* zp = z + zofs;
  float* op = out + zofs;
  double ls = 0.0;
  #pragma unroll 2
  for (int i16 = 0; i16 < 16; ++i16) {
    const int d4 = w * 64 + i16 * 4;
    const float4 q4 = *(const float4*)&rows[l * 260 + d4];
    #pragma unroll
    for (int e = 0; e < 4; ++e) {
      const int d = d4 + e;
      const float zv = zp[d * 1024];
      const float qv = ((const float*)&q4)[e];
      float df = qv - zv;
      asm volatile("" : "+v"(df));
      op[d * 1024] = zv + df;  // fl(z + fl(z_q - z))
      ls += (double)df * df;
    }
  }
  #pragma unroll
  for (int off = 32; off > 0; off >>= 1) ls += __shfl_down(ls, off);
  if (l == 0) atomicAdd(acc, ls);
}

__global__ void vq_fin(const double* __restrict__ acc, float* __restrict__ out) {
  if (threadIdx.x == 0)
    out[16777216] = (float)(1.25 * (*acc) * (1.0 / 16777216.0));
}

extern "C" void kernel_launch(void* const* d_in, const int* in_sizes, int n_in,
                              void* d_out, int out_size, void* d_ws, size_t ws_size,
                              hipStream_t stream) {
  const float* z = (const float*)d_in[0];
  const float* emb = (const float*)d_in[1];
  float* out = (float*)d_out;
  char* ws = (char*)d_ws;
  double* acc = (double*)(ws);
  int* widx = (int*)(ws + 64);
  float* e2 = (float*)(ws + 262208);
  float* z2 = (float*)(ws + 266304);
  int* gcnt = (int*)(ws + 528448);
  unsigned short* gcand = (unsigned short*)(ws + 790592);
  _Float16* Ef = (_Float16*)(ws + 2887744);

  hipFuncSetAttribute(reinterpret_cast<const void*>(vq_screen),
                      hipFuncAttributeMaxDynamicSharedMemorySize, SCR_LDS_BYTES);
  hipFuncSetAttribute(reinterpret_cast<const void*>(vq_rescore),
                      hipFuncAttributeMaxDynamicSharedMemorySize, RES_LDS_BYTES);
  hipFuncSetAttribute(reinterpret_cast<const void*>(vq_out),
                      hipFuncAttributeMaxDynamicSharedMemorySize, OUT_LDS_BYTES);

  hipMemsetAsync(ws, 0, 64, stream);
  vq_prep<<<1024, 256, 0, stream>>>(emb, Ef, e2);
  vq_z2<<<256, 256, 0, stream>>>(z, z2);
  vq_screen<<<1024, 256, SCR_LDS_BYTES, stream>>>(z, Ef, e2, z2, gcnt, gcand);
  vq_rescore<<<1024, 256, RES_LDS_BYTES, stream>>>(z, emb, e2, z2, gcnt, gcand,
                                                   widx, out);
  vq_out<<<1024, 256, OUT_LDS_BYTES, stream>>>(z, emb, widx, out, acc);
  vq_fin<<<1, 64, 0, stream>>>(acc, out);
}

// Round 11
// 287.037 us; speedup vs baseline: 2.3762x; 1.1519x over previous
//
#include <hip/hip_runtime.h>

// VectorQuantizer on MI355X — round 11: vq_z2 chain-split (16 threads/point,
// 4096 blocks -> full occupancy; bit-exact numpy pairwise order preserved).
// z: (64,256,32,32) f32; emb: (1024,256) f32.
// out (f32): [0,16777216) z_q_out | [16777216] loss | [16777217,+65536) indices
//
// ws layout (bytes):
//   0        double   loss_acc                 (memset 0)
//   64       int      widx[65536]
//   262208   float    e2[1024]                 (numpy-pairwise fp32)
//   266304   float    z2[65536]                (numpy-pairwise fp32)
//   528448   int      gcnt[65536]
//   790592   ushort   gcand[65536*16]
//   2887744  _Float16 Ef[1024*256]             (f16 RNE copy of emb)

typedef _Float16 f16x8 __attribute__((ext_vector_type(8)));
typedef float f32x4 __attribute__((ext_vector_type(4)));

#define VQ_W 1.5e-3f
#define SCR_LDS_BYTES 68096
#define RES_LDS_BYTES (65792 + 512)
#define OUT_LDS_BYTES 66560

// fl32(v*v) with a barrier so the product cannot be contracted into a later add.
__device__ __forceinline__ float sq_rnd(float v) {
  float y = v * v;
  asm volatile("" : "+v"(y));
  return y;
}

// numpy pairwise_sum over 256 fp32 squared terms (8-accumulator blocks of 128).
__device__ float np_pw256_sq(const float* base, int stride) {
  float tot0, tot1;
  {
    const float* a = base;
    float r[8];
    #pragma unroll
    for (int j = 0; j < 8; ++j) r[j] = sq_rnd(a[j * stride]);
    #pragma unroll 1
    for (int i = 8; i < 128; i += 8) {
      #pragma unroll
      for (int j = 0; j < 8; ++j) r[j] += sq_rnd(a[(i + j) * stride]);
    }
    tot0 = ((r[0] + r[1]) + (r[2] + r[3])) + ((r[4] + r[5]) + (r[6] + r[7]));
  }
  {
    const float* a = base + 128 * stride;
    float r[8];
    #pragma unroll
    for (int j = 0; j < 8; ++j) r[j] = sq_rnd(a[j * stride]);
    #pragma unroll 1
    for (int i = 8; i < 128; i += 8) {
      #pragma unroll
      for (int j = 0; j < 8; ++j) r[j] += sq_rnd(a[(i + j) * stride]);
    }
    tot1 = ((r[0] + r[1]) + (r[2] + r[3])) + ((r[4] + r[5]) + (r[6] + r[7]));
  }
  return tot0 + tot1;
}

__global__ __launch_bounds__(256) void vq_prep(const float* __restrict__ emb,
                                               _Float16* __restrict__ Ef,
                                               float* __restrict__ e2) {
  const int g = blockIdx.x * 256 + threadIdx.x;  // 0..262143
  Ef[g] = (_Float16)emb[g];                      // RNE v_cvt_f16_f32
  if (g < 1024) e2[g] = np_pw256_sq(emb + g * 256, 1);
}

// |z|^2 per point, numpy-pairwise, v3: 16 threads per point (one per accumulator
// chain), 16 points per block, 4096 blocks. Each chain r = sq(a[h*128+j]) +
// sq(a[..+8]) + ... (16 sequential terms) is EXACTLY one np accumulator; the
// per-point combine applies the same trees: ((r0+r1)+(r2+r3))+((r4+r5)+(r6+r7))
// per half, then tot0+tot1.
__global__ __launch_bounds__(256) void vq_z2(const float* __restrict__ z,
                                             float* __restrict__ z2) {
  __shared__ float sm[256];  // [chain c][point p] = sm[c*16+p]
  const int tid = threadIdx.x;
  const int p = tid & 15;    // point within group
  const int c = tid >> 4;    // chain 0..15: h = c>>3, j = c&7
  const int n0 = blockIdx.x * 16;
  const int n = n0 + p;
  const int bb = n >> 10, hw = n & 1023;
  const float* zp = z + bb * 262144 + hw;
  const int dbase = (c >> 3) * 128 + (c & 7);
  float r = sq_rnd(zp[dbase * 1024]);
  #pragma unroll
  for (int i = 1; i < 16; ++i) r += sq_rnd(zp[(dbase + 8 * i) * 1024]);
  sm[c * 16 + p] = r;
  __syncthreads();
  if (tid < 16) {
    const int pp = tid;
    float h0[8], h1[8];
    #pragma unroll
    for (int j = 0; j < 8; ++j) {
      h0[j] = sm[j * 16 + pp];
      h1[j] = sm[(8 + j) * 16 + pp];
    }
    const float tot0 = ((h0[0] + h0[1]) + (h0[2] + h0[3])) +
                       ((h0[4] + h0[5]) + (h0[6] + h0[7]));
    const float tot1 = ((h1[0] + h1[1]) + (h1[2] + h1[3])) +
                       ((h1[4] + h1[5]) + (h1[6] + h1[7]));
    z2[n0 + pp] = tot0 + tot1;
  }
}

// Screening v4 (r9-verified): f16 MFMA, block = 64 points x 1024 codes, pipelined
// (dbuf B, 2-deep reg staging, ONE barrier per phase). Chunk epilogue barrier-
// synced: wave mins -> atomicMin(runminU); barrier; collect with
// thr = true_prefix_min + W (superset of final-min window; typical cnt == 1).
__global__ __launch_bounds__(256, 2) void vq_screen(
    const float* __restrict__ z, const _Float16* __restrict__ Ef,
    const float* __restrict__ e2, const float* __restrict__ z2,
    int* __restrict__ gcnt, unsigned short* __restrict__ gcand) {
  extern __shared__ __align__(16) char smem[];
  // [0,32768) A; [32768,65536) B dbuf; 65536 runminU[64]; 65792 cnt[64]; 66048 cand[64][16]
  unsigned* runminU = (unsigned*)(smem + 65536);
  int* cnt = (int*)(smem + 65792);
  unsigned short* cand = (unsigned short*)(smem + 66048);

  const int tid = threadIdx.x;
  const int blk = blockIdx.x;
  const int n0 = blk * 64;
  const int bb = blk >> 4;
  const int hw0 = (blk & 15) * 64;
  const float* zb = z + bb * 262144 + hw0;

  if (tid < 64) { runminU[tid] = 0x7F800000u; cnt[tid] = 0; }

  {  // A stage: convert z tile to f16, swizzled rows
    const int p = tid & 63, dh = tid >> 6;
    #pragma unroll
    for (int dq = 0; dq < 8; ++dq) {
      const int d0 = dh * 64 + dq * 8;
      f16x8 hv;
      #pragma unroll
      for (int j = 0; j < 8; ++j) hv[j] = (_Float16)zb[(d0 + j) * 1024 + p];
      *(f16x8*)&smem[p * 512 + ((d0 * 2) ^ ((p & 7) * 16))] = hv;
    }
  }

  const int l = tid & 63;
  const int ln = l & 15;
  const int q = l >> 4;
  const int wc = tid >> 6;        // wave: codes wc*64 .. +63 per chunk
  const int xr = (l & 7) * 16;
  const int bswz = (l & 3) * 16;

  float z2r[4][4];
  #pragma unroll
  for (int fi = 0; fi < 4; ++fi)
    #pragma unroll
    for (int rg = 0; rg < 4; ++rg)
      z2r[fi][rg] = z2[n0 + fi * 16 + q * 4 + rg];

  f32x4 acc[4][4];
  #pragma unroll
  for (int fi = 0; fi < 4; ++fi)
    #pragma unroll
    for (int fj = 0; fj < 4; ++fj) acc[fi][fj] = (f32x4){0.f, 0.f, 0.f, 0.f};

  f16x8 stg[4];
  // prologue: tile 0 -> B0 ; tile 1 -> regs
  #pragma unroll
  for (int it = 0; it < 4; ++it) {
    const int c2 = it * 256 + tid;
    const int r = c2 >> 2, s = c2 & 3;
    stg[it] = *(const f16x8*)&Ef[r * 256 + (s ^ (r & 3)) * 8];  // t=0: cc=0,ph=0
  }
  #pragma unroll
  for (int it = 0; it < 4; ++it)
    *(f16x8*)&smem[32768 + it * 4096 + tid * 16] = stg[it];
  #pragma unroll
  for (int it = 0; it < 4; ++it) {
    const int c2 = it * 256 + tid;
    const int r = c2 >> 2, s = c2 & 3;
    stg[it] = *(const f16x8*)&Ef[r * 256 + 32 + (s ^ (r & 3)) * 8];  // t=1: ph=1
  }
  __syncthreads();

  for (int p = 0; p < 32; ++p) {
    char* Bw = smem + 32768 + (((p & 1) ^ 1) << 14);
    const char* Br = smem + 32768 + ((p & 1) << 14);
    if (p < 31) {  // ds_write tile p+1 (that buffer last read in phase p-1)
      #pragma unroll
      for (int it = 0; it < 4; ++it)
        *(f16x8*)&Bw[it * 4096 + tid * 16] = stg[it];
    }
    if (p < 30) {  // issue global loads for tile p+2
      const int t = p + 2;
      const int cct = t >> 3, pht = t & 7;
      #pragma unroll
      for (int it = 0; it < 4; ++it) {
        const int c2 = it * 256 + tid;
        const int r = c2 >> 2, s = c2 & 3;
        stg[it] = *(const f16x8*)&Ef[(cct * 256 + r) * 256 + pht * 32 +
                                     (s ^ (r & 3)) * 8];
      }
    }
    {  // compute phase p from Br
      const int ph = p & 7;
      f16x8 aF[4], bF[4];
      const int ab = (ph * 64 + q * 16) ^ xr;
      #pragma unroll
      for (int fi = 0; fi < 4; ++fi)
        aF[fi] = *(const f16x8*)&smem[(fi * 16 + ln) * 512 + ab];
      const int qb = (q * 16) ^ bswz;
      #pragma unroll
      for (int fj = 0; fj < 4; ++fj)
        bF[fj] = *(const f16x8*)&Br[(wc * 64 + fj * 16 + ln) * 64 + qb];
      #pragma unroll
      for (int fi = 0; fi < 4; ++fi)
        #pragma unroll
        for (int fj = 0; fj < 4; ++fj)
          acc[fi][fj] = __builtin_amdgcn_mfma_f32_16x16x32_f16(
              aF[fi], bF[fj], acc[fi][fj], 0, 0, 0);
    }
    if ((p & 7) == 7) {  // chunk epilogue: exact prefix-min via one barrier
      const int cc = p >> 3;
      const int cbase = cc * 256 + wc * 64 + ln;
      float e2v[4];
      #pragma unroll
      for (int fj = 0; fj < 4; ++fj) e2v[fj] = e2[cbase + fj * 16];
      // Phase 1: wave-local mins -> atomicMin into runminU
      #pragma unroll
      for (int fi = 0; fi < 4; ++fi) {
        #pragma unroll
        for (int rg = 0; rg < 4; ++rg) {
          float rm = 3.4e38f;
          #pragma unroll
          for (int fj = 0; fj < 4; ++fj)
            rm = fminf(rm, fmaf(-2.f, acc[fi][fj][rg], z2r[fi][rg] + e2v[fj]));
          rm = fminf(rm, __shfl_xor(rm, 1));
          rm = fminf(rm, __shfl_xor(rm, 2));
          rm = fminf(rm, __shfl_xor(rm, 4));
          rm = fminf(rm, __shfl_xor(rm, 8));
          if (ln == 0)
            atomicMin(&runminU[fi * 16 + q * 4 + rg], __float_as_uint(rm));
        }
      }
      __syncthreads();  // runminU now = true min over ALL codes up to chunk cc
      // Phase 2: collect candidates against the exact prefix min
      #pragma unroll
      for (int fi = 0; fi < 4; ++fi) {
        #pragma unroll
        for (int rg = 0; rg < 4; ++rg) {
          const int row = fi * 16 + q * 4 + rg;
          const float thr = __uint_as_float(runminU[row]) + VQ_W;
          #pragma unroll
          for (int fj = 0; fj < 4; ++fj) {
            const float sv = fmaf(-2.f, acc[fi][fj][rg], z2r[fi][rg] + e2v[fj]);
            if (sv <= thr) {
              const int slot = atomicAdd(&cnt[row], 1);
              if (slot < 16)
                cand[row * 16 + slot] = (unsigned short)(cbase + fj * 16);
            }
          }
        }
        #pragma unroll
        for (int fj = 0; fj < 4; ++fj) acc[fi][fj] = (f32x4){0.f, 0.f, 0.f, 0.f};
      }
    }
    __syncthreads();
  }

  if (tid < 64) gcnt[n0 + tid] = cnt[tid];
  {
    const int rr = tid >> 2, si = (tid & 3) * 4;
    *(uint2*)&gcand[(n0 + rr) * 16 + si] = *(const uint2*)&cand[rr * 16 + si];
  }
}

// Rescore (r6-verified): block = 64 points, z-tile in LDS, 4 threads/point split
// candidates; merge via LDS u64 atomicMin on (score_bits<<10)|k. Writes indices
// output directly.
__global__ __launch_bounds__(256) void vq_rescore(
    const float* __restrict__ z, const float* __restrict__ emb,
    const float* __restrict__ e2, const float* __restrict__ z2,
    const int* __restrict__ gcnt, const unsigned short* __restrict__ gcand,
    int* __restrict__ widx, float* __restrict__ out) {
  extern __shared__ __align__(16) char rsmem[];
  float* zt = (float*)rsmem;                                        // [64][257]
  unsigned long long* best = (unsigned long long*)(rsmem + 65792);  // [64]

  const int tid = threadIdx.x;
  const int w = tid >> 6;
  const int l = tid & 63;
  const int n0 = blockIdx.x << 6;
  const int bb = n0 >> 10, hw0 = n0 & 1023;
  const int n = n0 + l;

  const int c = gcnt[n];
  if (!__any(c >= 2)) {  // block-uniform: all waves see identical l-range
    if (w == 0) {
      const int v = gcand[n * 16];
      widx[n] = v;
      out[16777217 + n] = (float)v;
    }
    return;
  }

  {  // stage z tile
    const float* zb = z + bb * 262144 + hw0;
    #pragma unroll 8
    for (int it = 0; it < 64; ++it) {
      const int d = it * 4 + w;
      zt[l * 257 + d] = zb[d * 1024 + l];
    }
  }
  if (tid < 64) best[tid] = ~0ULL;
  __syncthreads();

  if (c >= 2) {
    const float z2n = z2[n];
    const float* zrow = &zt[l * 257];
    if (c <= 16) {
      for (int s = w; s < c; s += 4) {
        const int k = gcand[n * 16 + s];
        const float* ep = emb + k * 256;
        float a = 0.f;
        #pragma unroll 4
        for (int d = 0; d < 256; ++d) a = fmaf(zrow[d], ep[d], a);
        const float sv = fmaf(-2.f, a, z2n + e2[k]);
        const unsigned long long key =
            ((unsigned long long)__float_as_uint(sv) << 10) | (unsigned)k;
        atomicMin(&best[l], key);
      }
    } else {  // overflow fallback: exact full scan
      for (int k = w; k < 1024; k += 4) {
        const float* ep = emb + k * 256;
        float a = 0.f;
        #pragma unroll 4
        for (int d = 0; d < 256; ++d) a = fmaf(zrow[d], ep[d], a);
        const float sv = fmaf(-2.f, a, z2n + e2[k]);
        const unsigned long long key =
            ((unsigned long long)__float_as_uint(sv) << 10) | (unsigned)k;
        atomicMin(&best[l], key);
      }
    }
  }
  __syncthreads();
  if (tid < 64) {
    const int cc = gcnt[n0 + tid];
    const int v = (cc == 1) ? (int)gcand[(n0 + tid) * 16]
                            : (int)(best[tid] & 1023ULL);
    widx[n0 + tid] = v;
    out[16777217 + n0 + tid] = (float)v;
  }
}

// Output + loss (r3-verified). Gather 64 emb rows into LDS row-coalesced, then
// transpose-read (stride 260) + coalesced global write.
__global__ __launch_bounds__(256) void vq_out(const float* __restrict__ z,
                                              const float* __restrict__ emb,
                                              const int* __restrict__ widx,
                                              float* __restrict__ out,
                                              double* __restrict__ acc) {
  extern __shared__ float rows[];  // [64][260]
  const int tid = threadIdx.x;
  const int w = tid >> 6, l = tid & 63;
  const int n0 = blockIdx.x << 6;
  const int bb = n0 >> 10, hw0 = n0 & 1023;

  #pragma unroll 4
  for (int rr = 0; rr < 16; ++rr) {
    const int r = rr * 4 + w;
    const int idx = widx[n0 + r];
    const float4 ev = *(const float4*)&emb[idx * 256 + l * 4];
    *(float4*)&rows[r * 260 + l * 4] = ev;
  }
  __syncthreads();

  const int zofs = bb * 262144 + hw0 + l;
  const float* zp = z + zofs;
  float* op = out + zofs;
  double ls = 0.0;
  #pragma unroll 2
  for (int i16 = 0; i16 < 16; ++i16) {
    const int d4 = w * 64 + i16 * 4;
    const float4 q4 = *(const float4*)&rows[l * 260 + d4];
    #pragma unroll
    for (int e = 0; e < 4; ++e) {
      const int d = d4 + e;
      const float zv = zp[d * 1024];
      const float qv = ((const float*)&q4)[e];
      float df = qv - zv;
      asm volatile("" : "+v"(df));
      op[d * 1024] = zv + df;  // fl(z + fl(z_q - z))
      ls += (double)df * df;
    }
  }
  #pragma unroll
  for (int off = 32; off > 0; off >>= 1) ls += __shfl_down(ls, off);
  if (l == 0) atomicAdd(acc, ls);
}

__global__ void vq_fin(const double* __restrict__ acc, float* __restrict__ out) {
  if (threadIdx.x == 0)
    out[16777216] = (float)(1.25 * (*acc) * (1.0 / 16777216.0));
}

extern "C" void kernel_launch(void* const* d_in, const int* in_sizes, int n_in,
                              void* d_out, int out_size, void* d_ws, size_t ws_size,
                              hipStream_t stream) {
  const float* z = (const float*)d_in[0];
  const float* emb = (const float*)d_in[1];
  float* out = (float*)d_out;
  char* ws = (char*)d_ws;
  double* acc = (double*)(ws);
  int* widx = (int*)(ws + 64);
  float* e2 = (float*)(ws + 262208);
  float* z2 = (float*)(ws + 266304);
  int* gcnt = (int*)(ws + 528448);
  unsigned short* gcand = (unsigned short*)(ws + 790592);
  _Float16* Ef = (_Float16*)(ws + 2887744);

  hipFuncSetAttribute(reinterpret_cast<const void*>(vq_screen),
                      hipFuncAttributeMaxDynamicSharedMemorySize, SCR_LDS_BYTES);
  hipFuncSetAttribute(reinterpret_cast<const void*>(vq_rescore),
                      hipFuncAttributeMaxDynamicSharedMemorySize, RES_LDS_BYTES);
  hipFuncSetAttribute(reinterpret_cast<const void*>(vq_out),
                      hipFuncAttributeMaxDynamicSharedMemorySize, OUT_LDS_BYTES);

  hipMemsetAsync(ws, 0, 64, stream);
  vq_prep<<<1024, 256, 0, stream>>>(emb, Ef, e2);
  vq_z2<<<4096, 256, 0, stream>>>(z, z2);
  vq_screen<<<1024, 256, SCR_LDS_BYTES, stream>>>(z, Ef, e2, z2, gcnt, gcand);
  vq_rescore<<<1024, 256, RES_LDS_BYTES, stream>>>(z, emb, e2, z2, gcnt, gcand,
                                                   widx, out);
  vq_out<<<1024, 256, OUT_LDS_BYTES, stream>>>(z, emb, widx, out, acc);
  vq_fin<<<1, 64, 0, stream>>>(acc, out);
}